// Round 8
// baseline (39.036 us; speedup 1.0000x reference)
//
#include <hip/hip_runtime.h>

// out[b, e] = sum_d x[b, d] * T[g[b] % G, d, e]
// B=128, D=1024, G=40, f32.
//
// R7 structure + grid rebalance: 1280 blocks (= 5.0/CU exactly) instead of
// 640 (= 2.5/CU -> 3-round makespan quantization). Block = (group gi,
// 32-column stripe). Threads 256 = 32 d-slices x 8 e-threads; each thread
// owns 4 cols (float4) and 32 rows; in-block LDS reduce across d-slices
// writes out directly. T loads nontemporal (single-use stream).

#define B_DIM   128
#define D_DIM   1024
#define G_DIM   40
#define SMAX    8      // samples per pass (loop handles rare >8 groups)
#define ECH     32     // column stripes
#define ECOLS   32     // columns per block
#define DSL     32     // d-slices per block (32 rows each)
#define THREADS 256

// native clang vector type: __builtin_nontemporal_load rejects HIP_vector_type
typedef float f4 __attribute__((ext_vector_type(4)));

__global__ __launch_bounds__(THREADS) void leqfc_fused(
    const float* __restrict__ x,
    const int* __restrict__ g,
    const float* __restrict__ T,
    float* __restrict__ out)
{
    const int gi  = blockIdx.x;          // 0..39
    const int e0  = blockIdx.y * ECOLS;  // column stripe base
    const int tid = threadIdx.x;
    const int sl  = tid >> 3;            // d-slice 0..31 (rows sl*32 .. +31)
    const int eth = tid & 7;             // e-thread: cols e0 + eth*4 .. +3

    // xs[8][1024] (32 KB) during the d-loop; red[8][32][32] (32 KB) after.
    __shared__ float smem[SMAX * D_DIM];
    __shared__ int   mem[B_DIM];
    __shared__ int   cnt;

    if (tid == 0) cnt = 0;
    __syncthreads();
    if (tid < B_DIM) {
        if ((g[tid] % G_DIM) == gi)
            mem[atomicAdd(&cnt, 1)] = tid;   // slot order races; per-sample
    }                                        // numerics are slot-invariant
    __syncthreads();
    const int m = cnt;

    const f4* __restrict__ x4 = reinterpret_cast<const f4*>(x);
    const f4* __restrict__ Tp = reinterpret_cast<const f4*>(
        T + (size_t)gi * D_DIM * D_DIM + (size_t)(sl * 32) * D_DIM + e0) + eth;
    f4* smem4 = reinterpret_cast<f4*>(smem);

    for (int s0 = 0; s0 < m; s0 += SMAX) {
        const int mc = min(SMAX, m - s0);

        __syncthreads();   // previous pass done with smem
        // stage xs[j][0..1023] for mc samples: 2048 float4 slots, 8/thread
        #pragma unroll
        for (int k = 0; k < 8; ++k) {
            const int fq = tid + k * THREADS;   // 0..2047
            const int j  = fq >> 8;
            const int dq = fq & 255;
            smem4[fq] = (j < mc) ? x4[(size_t)mem[s0 + j] * (D_DIM / 4) + dq]
                                 : (f4)(0.f);
        }
        __syncthreads();

        f4 acc[SMAX];
        #pragma unroll
        for (int j = 0; j < SMAX; ++j) acc[j] = (f4)(0.f);

        // 32 rows per thread, 4 rows per iteration; nt loads (zero reuse)
        #pragma unroll 4
        for (int k = 0; k < 8; ++k) {
            const f4 t0 = __builtin_nontemporal_load(&Tp[(size_t)(4 * k + 0) * (D_DIM / 4)]);
            const f4 t1 = __builtin_nontemporal_load(&Tp[(size_t)(4 * k + 1) * (D_DIM / 4)]);
            const f4 t2 = __builtin_nontemporal_load(&Tp[(size_t)(4 * k + 2) * (D_DIM / 4)]);
            const f4 t3 = __builtin_nontemporal_load(&Tp[(size_t)(4 * k + 3) * (D_DIM / 4)]);
            const int dq = sl * 8 + k;   // f4 index of rows 4k..4k+3 in xs
            #pragma unroll
            for (int j = 0; j < SMAX; ++j) {
                const f4 xv = smem4[j * (D_DIM / 4) + dq];  // broadcast read
                acc[j].x = fmaf(xv.x, t0.x, fmaf(xv.y, t1.x, fmaf(xv.z, t2.x, fmaf(xv.w, t3.x, acc[j].x))));
                acc[j].y = fmaf(xv.x, t0.y, fmaf(xv.y, t1.y, fmaf(xv.z, t2.y, fmaf(xv.w, t3.y, acc[j].y))));
                acc[j].z = fmaf(xv.x, t0.z, fmaf(xv.y, t1.z, fmaf(xv.z, t2.z, fmaf(xv.w, t3.z, acc[j].z))));
                acc[j].w = fmaf(xv.x, t0.w, fmaf(xv.y, t1.w, fmaf(xv.z, t2.w, fmaf(xv.w, t3.w, acc[j].w))));
            }
        }

        __syncthreads();   // all xs reads complete; smem becomes red[8][32][32]
        #pragma unroll
        for (int j = 0; j < SMAX; ++j)
            smem4[(j * DSL + sl) * (ECOLS / 4) + eth] = acc[j];
        __syncthreads();

        // fold 32 d-slices: 256 outputs (8 samples x 32 cols), 1 per thread
        {
            const int j = tid >> 5;          // sample 0..7
            const int c = tid & 31;          // column within stripe
            if (j < mc) {
                float s = 0.f;
                #pragma unroll
                for (int ss = 0; ss < DSL; ++ss)
                    s += smem[(j * DSL + ss) * ECOLS + c];
                __builtin_nontemporal_store(
                    s, &out[(size_t)mem[s0 + j] * D_DIM + e0 + c]);
            }
        }
    }
}

extern "C" void kernel_launch(void* const* d_in, const int* in_sizes, int n_in,
                              void* d_out, int out_size, void* d_ws, size_t ws_size,
                              hipStream_t stream)
{
    const float* x = (const float*)d_in[0];
    const int*   g = (const int*)d_in[1];
    const float* T = (const float*)d_in[2];
    float* out = (float*)d_out;

    dim3 grid(G_DIM, ECH);   // 40 x 32 = 1280 blocks = 5.0 per CU
    leqfc_fused<<<grid, THREADS, 0, stream>>>(x, g, T, out);
}

// Round 9
// 38.138 us; speedup vs baseline: 1.0235x; 1.0235x over previous
//
#include <hip/hip_runtime.h>

// out[b, e] = sum_d x[b, d] * T[g[b] % G, d, e]
// B=128, D=1024, G=40, f32.
//
// R7's proven geometry (ECOLS=64 -> 256B contiguous per wave-row, nt loads)
// but split d in half: grid 40x16x2 = 1280 blocks = 5 waves/SIMD (vs 2.5)
// to test the aggregate-MLP theory. xs drops to 16 KB -> ~17 KB LDS.
// Cross-dhalf combine: 1 MB partials in d_ws + small reduce kernel.

#define B_DIM   128
#define D_DIM   1024
#define G_DIM   40
#define SMAX    8      // samples per pass (loop handles rare >8 groups)
#define ECH     16     // column stripes
#define ECOLS   64     // columns per block
#define DHALF   512    // rows per block
#define NSL     16     // d-slices per block (32 rows each)
#define THREADS 256

typedef float f4 __attribute__((ext_vector_type(4)));

__global__ __launch_bounds__(THREADS) void leqfc_main(
    const float* __restrict__ x,
    const int* __restrict__ g,
    const float* __restrict__ T,
    float* __restrict__ part)   // [2][B_DIM][D_DIM]
{
    const int gi  = blockIdx.x;          // 0..39
    const int e0  = blockIdx.y * ECOLS;  // column stripe base
    const int dh  = blockIdx.z;          // d half 0/1
    const int d0  = dh * DHALF;
    const int tid = threadIdx.x;
    const int sl  = tid >> 4;            // d-slice 0..15 (rows d0+sl*32 .. +31)
    const int eth = tid & 15;            // e-thread: cols e0 + eth*4 .. +3

    __shared__ float xs[SMAX * DHALF];   // 16 KB
    __shared__ f4    red[SMAX * 4 * 16]; // 8 KB: [j][wave][eth]
    __shared__ int   mem[B_DIM];
    __shared__ int   cnt;

    if (tid == 0) cnt = 0;
    __syncthreads();
    if (tid < B_DIM) {
        if ((g[tid] % G_DIM) == gi)
            mem[atomicAdd(&cnt, 1)] = tid;   // slot order races; per-sample
    }                                        // numerics are slot-invariant
    __syncthreads();
    const int m = cnt;

    const f4* __restrict__ x4 = reinterpret_cast<const f4*>(x);
    const f4* __restrict__ Tp = reinterpret_cast<const f4*>(
        T + (size_t)gi * D_DIM * D_DIM + (size_t)(d0 + sl * 32) * D_DIM + e0) + eth;
    f4* xs4 = reinterpret_cast<f4*>(xs);

    const int wv = tid >> 6;             // wave 0..3 (covers sl 4w..4w+3)
    const int ln = tid & 63;

    for (int s0 = 0; s0 < m; s0 += SMAX) {
        const int mc = min(SMAX, m - s0);

        __syncthreads();   // previous pass done with xs
        // stage xs[j][0..511] for mc samples: 1024 f4 slots, 4/thread
        #pragma unroll
        for (int k = 0; k < 4; ++k) {
            const int fq = tid + k * THREADS;   // 0..1023
            const int j  = fq >> 7;             // sample
            const int dq = fq & 127;            // f4 within half-row
            xs4[fq] = (j < mc)
                ? x4[(size_t)mem[s0 + j] * (D_DIM / 4) + dh * (DHALF / 4) + dq]
                : (f4)(0.f);
        }
        __syncthreads();

        f4 acc[SMAX];
        #pragma unroll
        for (int j = 0; j < SMAX; ++j) acc[j] = (f4)(0.f);

        // 32 rows per thread, 4 rows per iteration; nt loads (zero reuse)
        #pragma unroll 4
        for (int k = 0; k < 8; ++k) {
            const f4 t0 = __builtin_nontemporal_load(&Tp[(size_t)(4 * k + 0) * (D_DIM / 4)]);
            const f4 t1 = __builtin_nontemporal_load(&Tp[(size_t)(4 * k + 1) * (D_DIM / 4)]);
            const f4 t2 = __builtin_nontemporal_load(&Tp[(size_t)(4 * k + 2) * (D_DIM / 4)]);
            const f4 t3 = __builtin_nontemporal_load(&Tp[(size_t)(4 * k + 3) * (D_DIM / 4)]);
            const int dq = sl * 8 + k;          // f4 idx of rows 4k..4k+3 in xs
            #pragma unroll
            for (int j = 0; j < SMAX; ++j) {
                const f4 xv = xs4[j * (DHALF / 4) + dq];  // broadcast read
                acc[j].x = fmaf(xv.x, t0.x, fmaf(xv.y, t1.x, fmaf(xv.z, t2.x, fmaf(xv.w, t3.x, acc[j].x))));
                acc[j].y = fmaf(xv.x, t0.y, fmaf(xv.y, t1.y, fmaf(xv.z, t2.y, fmaf(xv.w, t3.y, acc[j].y))));
                acc[j].z = fmaf(xv.x, t0.z, fmaf(xv.y, t1.z, fmaf(xv.z, t2.z, fmaf(xv.w, t3.z, acc[j].z))));
                acc[j].w = fmaf(xv.x, t0.w, fmaf(xv.y, t1.w, fmaf(xv.z, t2.w, fmaf(xv.w, t3.w, acc[j].w))));
            }
        }

        // fold the 4 in-wave d-slices (lanes differ by 16, 32 in lane id)
        #pragma unroll
        for (int j = 0; j < SMAX; ++j) {
            #pragma unroll
            for (int c = 0; c < 4; ++c) {
                float v = acc[j][c];
                v += __shfl_xor(v, 16);
                v += __shfl_xor(v, 32);
                acc[j][c] = v;
            }
        }
        // lanes 0..15 of each wave hold the wave-partial for eth=ln
        if (ln < 16) {
            #pragma unroll
            for (int j = 0; j < SMAX; ++j)
                red[(j * 4 + wv) * 16 + ln] = acc[j];
        }
        __syncthreads();

        // fold 4 waves: 512 outputs = 128 f4 (8 samples x 16 eth), 1 per thread<128
        if (tid < SMAX * 16) {
            const int j = tid >> 4;
            const int e = tid & 15;
            if (j < mc) {
                f4 s = red[(j * 4 + 0) * 16 + e];
                #pragma unroll
                for (int w = 1; w < 4; ++w) {
                    const f4 v = red[(j * 4 + w) * 16 + e];
                    s.x += v.x; s.y += v.y; s.z += v.z; s.w += v.w;
                }
                f4* o = reinterpret_cast<f4*>(
                    part + ((size_t)dh * B_DIM + mem[s0 + j]) * D_DIM + e0) + e;
                *o = s;   // regular store: 1 MB, stays L2-resident for reduce
            }
        }
        __syncthreads();   // red reused next pass
    }
}

__global__ __launch_bounds__(256) void leqfc_reduce(
    const float* __restrict__ part, float* __restrict__ out)
{
    const int idx = blockIdx.x * 256 + threadIdx.x;   // over B*D/4 f4 slots
    const f4* p4 = reinterpret_cast<const f4*>(part);
    const f4 a = p4[idx];
    const f4 b = p4[(size_t)(B_DIM * D_DIM / 4) + idx];
    f4 s; s.x = a.x + b.x; s.y = a.y + b.y; s.z = a.z + b.z; s.w = a.w + b.w;
    __builtin_nontemporal_store(s, &reinterpret_cast<f4*>(out)[idx]);
}

extern "C" void kernel_launch(void* const* d_in, const int* in_sizes, int n_in,
                              void* d_out, int out_size, void* d_ws, size_t ws_size,
                              hipStream_t stream)
{
    const float* x = (const float*)d_in[0];
    const int*   g = (const int*)d_in[1];
    const float* T = (const float*)d_in[2];
    float* out  = (float*)d_out;
    float* part = (float*)d_ws;   // needs 2*128*1024*4 = 1 MB (ws is ~hundreds MB)

    dim3 grid(G_DIM, ECH, 2);     // 40 x 16 x 2 = 1280 blocks
    leqfc_main<<<grid, THREADS, 0, stream>>>(x, g, T, part);
    leqfc_reduce<<<(B_DIM * D_DIM / 4) / 256, 256, 0, stream>>>(part, out);
}

// Round 10
// 30.576 us; speedup vs baseline: 1.2767x; 1.2473x over previous
//
#include <hip/hip_runtime.h>

// out[b, e] = sum_d x[b, d] * T[g[b] % G, d, e]
// B=128, D=1024, G=40, f32.
//
// Best measured structure (R7, 30.5 us = ~5.25 TB/s read stream, 84% of the
// measured achievable HBM ceiling). Block = (group gi, 64-column stripe).
// Threads 256 = 16 d-slices x 16 e-threads; each thread owns 4 cols (float4)
// and 64 rows; in-block LDS reduce across d-slices writes out directly.
// T loads nontemporal (single-use stream). Probed-and-rejected variants:
// 32-col stripes (R8: -28%), d-split + partials/reduce (R9: -25%),
// pass-flattened grid (R5: -6%), dbuf/prefetch pipeline (R3: -25%).

#define B_DIM   128
#define D_DIM   1024
#define G_DIM   40
#define SMAX    8      // samples per pass (loop handles rare >8 groups)
#define ECH     16     // column stripes
#define ECOLS   64     // columns per block
#define DSL     16     // d-slices per block
#define THREADS 256

// native clang vector type: __builtin_nontemporal_load rejects HIP_vector_type
typedef float f4 __attribute__((ext_vector_type(4)));

__global__ __launch_bounds__(THREADS) void leqfc_fused(
    const float* __restrict__ x,
    const int* __restrict__ g,
    const float* __restrict__ T,
    float* __restrict__ out)
{
    const int gi  = blockIdx.x;          // 0..39
    const int e0  = blockIdx.y * ECOLS;  // column stripe base
    const int tid = threadIdx.x;
    const int sl  = tid >> 4;            // d-slice 0..15 (rows sl*64 .. +63)
    const int eth = tid & 15;            // e-thread: cols e0 + eth*4 .. +3

    // xs[8][1024] (32 KB) during the d-loop; red[8][16][64] (32 KB) after.
    __shared__ float smem[SMAX * D_DIM];
    __shared__ int   mem[B_DIM];
    __shared__ int   cnt;

    if (tid == 0) cnt = 0;
    __syncthreads();
    if (tid < B_DIM) {
        if ((g[tid] % G_DIM) == gi)
            mem[atomicAdd(&cnt, 1)] = tid;   // slot order races; per-sample
    }                                        // numerics are slot-invariant
    __syncthreads();
    const int m = cnt;

    const f4* __restrict__ x4 = reinterpret_cast<const f4*>(x);
    const f4* __restrict__ Tp = reinterpret_cast<const f4*>(
        T + (size_t)gi * D_DIM * D_DIM + (size_t)(sl * 64) * D_DIM + e0) + eth;
    f4* smem4 = reinterpret_cast<f4*>(smem);

    for (int s0 = 0; s0 < m; s0 += SMAX) {
        const int mc = min(SMAX, m - s0);

        __syncthreads();   // previous pass done with smem
        // stage xs[j][0..1023] for mc samples: 2048 float4 slots, 8/thread
        #pragma unroll
        for (int k = 0; k < 8; ++k) {
            const int fq = tid + k * THREADS;   // 0..2047
            const int j  = fq >> 8;
            const int dq = fq & 255;
            smem4[fq] = (j < mc) ? x4[(size_t)mem[s0 + j] * (D_DIM / 4) + dq]
                                 : (f4)(0.f);
        }
        __syncthreads();

        f4 acc[SMAX];
        #pragma unroll
        for (int j = 0; j < SMAX; ++j) acc[j] = (f4)(0.f);

        // 64 rows per thread, 4 rows per iteration; nt loads (zero reuse)
        #pragma unroll 4
        for (int k = 0; k < 16; ++k) {
            const f4 t0 = __builtin_nontemporal_load(&Tp[(size_t)(4 * k + 0) * (D_DIM / 4)]);
            const f4 t1 = __builtin_nontemporal_load(&Tp[(size_t)(4 * k + 1) * (D_DIM / 4)]);
            const f4 t2 = __builtin_nontemporal_load(&Tp[(size_t)(4 * k + 2) * (D_DIM / 4)]);
            const f4 t3 = __builtin_nontemporal_load(&Tp[(size_t)(4 * k + 3) * (D_DIM / 4)]);
            const int dq = sl * 16 + k;   // float4 index of rows 4k..4k+3 in xs
            #pragma unroll
            for (int j = 0; j < SMAX; ++j) {
                const f4 xv = smem4[j * (D_DIM / 4) + dq];  // broadcast read
                acc[j].x = fmaf(xv.x, t0.x, fmaf(xv.y, t1.x, fmaf(xv.z, t2.x, fmaf(xv.w, t3.x, acc[j].x))));
                acc[j].y = fmaf(xv.x, t0.y, fmaf(xv.y, t1.y, fmaf(xv.z, t2.y, fmaf(xv.w, t3.y, acc[j].y))));
                acc[j].z = fmaf(xv.x, t0.z, fmaf(xv.y, t1.z, fmaf(xv.z, t2.z, fmaf(xv.w, t3.z, acc[j].z))));
                acc[j].w = fmaf(xv.x, t0.w, fmaf(xv.y, t1.w, fmaf(xv.z, t2.w, fmaf(xv.w, t3.w, acc[j].w))));
            }
        }

        __syncthreads();   // all xs reads complete; smem becomes red[]
        #pragma unroll
        for (int j = 0; j < SMAX; ++j)
            smem4[(j * DSL + sl) * (ECOLS / 4) + eth] = acc[j];
        __syncthreads();

        // fold 16 d-slices: 512 outputs (8 samples x 64 cols), 2 per thread
        #pragma unroll
        for (int o2 = 0; o2 < 2; ++o2) {
            const int o = tid + o2 * THREADS;   // 0..511
            const int j = o >> 6;
            const int c = o & 63;
            if (j < mc) {
                float s = 0.f;
                #pragma unroll
                for (int ss = 0; ss < DSL; ++ss)
                    s += smem[(j * DSL + ss) * ECOLS + c];
                __builtin_nontemporal_store(
                    s, &out[(size_t)mem[s0 + j] * D_DIM + e0 + c]);
            }
        }
    }
}

extern "C" void kernel_launch(void* const* d_in, const int* in_sizes, int n_in,
                              void* d_out, int out_size, void* d_ws, size_t ws_size,
                              hipStream_t stream)
{
    const float* x = (const float*)d_in[0];
    const int*   g = (const int*)d_in[1];
    const float* T = (const float*)d_in[2];
    float* out = (float*)d_out;

    dim3 grid(G_DIM, ECH);   // 40 x 16 = 640 blocks
    leqfc_fused<<<grid, THREADS, 0, stream>>>(x, g, T, out);
}